// Round 8
// baseline (356.666 us; speedup 1.0000x reference)
//
#include <hip/hip_runtime.h>
#include <stdint.h>

// Masked cumulative sum along dim=1 — two-kernel reduce-then-scan, COARSE.
//   x:    (256, 131072) float32
//   mask: (256, 131072) int32 (0/1)
//   out:  (256, 131072) float32
//
// Round-8: coarsen round-7's structure 8x. Round-7 counters showed kernel A
// at 95 us / 1.4 TB/s / occupancy 68% / VALU 7% — 16384 tiny blocks (48 KB
// each) are launch/latency-bound: a block's life is one load-latency + a
// reduce, and HBM idles between block generations. Now 2048 blocks per
// kernel, each owning a contiguous 16384-elem segment walked in 8 chunks
// with next-chunk prefetch (the round-0 pattern that sustained 2.2 TB/s
// with only 256 blocks). 2048 blocks x 4 waves = 32 waves/CU, each with
// loads continuously in flight.
//
//   Kernel A: per-segment masked totals. Reads 268 MB, writes 8 KB.
//   Kernel B: per-block prefix = sum of <=7 row totals (uniform, L2-hot),
//             then serial scan of its 8 chunks with running carry.
//             Re-reads x+mask (L3-hot: A just touched them; round-7 measured
//             FETCH at exactly half = L3 retained), NT-stores 134 MB out.
//
// Kernel boundary on the same stream orders A's totals before B — no
// XCD-coherence hazard, no dispatch-order assumption, no atomics, no spin,
// no memset; replay-safe (totals written-before-read every launch).
// ws_size guarded; fallback to the harness-verified row-per-block kernel.

#define B_ROWS  256
#define N_COLS  131072
#define BLOCK   256
#define VPT     8                  // elems/thread/chunk (2x float4)
#define CHUNK   (BLOCK * VPT)      // 2048 elems
#define ITERS   8                  // chunks per segment
#define SEG     (CHUNK * ITERS)    // 16384 elems per block
#define SEGS    (N_COLS / SEG)     // 8 segments per row
#define NWAVES  (BLOCK / 64)       // 4
#define GRID_AB (B_ROWS * SEGS)    // 2048 blocks

typedef float nativef4 __attribute__((ext_vector_type(4)));

__device__ __forceinline__ float wave_incl_scan(float v, int lane) {
    #pragma unroll
    for (int d = 1; d < 64; d <<= 1) {
        const float y = __shfl_up(v, d, 64);
        if (lane >= d) v += y;
    }
    return v;
}

// ---------------------------------------------------------------------------
// Kernel A: per-segment masked totals (8 pipelined chunks per block).
// ---------------------------------------------------------------------------
__global__ __launch_bounds__(BLOCK, 8)
void seg_totals(const float* __restrict__ x,
                const int*   __restrict__ mask,
                float*       __restrict__ totals)
{
    __shared__ float s_wsum[NWAVES];

    const int tid  = threadIdx.x;
    const int lane = tid & 63;
    const int wave = tid >> 6;
    const int bid  = blockIdx.x;
    const int row  = bid >> 3;             // bid / SEGS
    const int seg  = bid & (SEGS - 1);     // bid % SEGS

    const size_t base = (size_t)row * N_COLS + (size_t)seg * SEG;
    const float4* __restrict__ x4 = (const float4*)(x + base);
    const int4*   __restrict__ m4 = (const int4*)(mask + base);

    float acc = 0.0f;

    // Prefetch chunk 0.
    float4 xa = x4[tid];
    int4   ma = m4[tid];
    float4 xb = x4[BLOCK + tid];
    int4   mb = m4[BLOCK + tid];

    for (int t = 0; t < ITERS; ++t) {
        const float4 cxa = xa; const int4 cma = ma;
        const float4 cxb = xb; const int4 cmb = mb;
        if (t + 1 < ITERS) {
            const int nb = (t + 1) * (2 * BLOCK) + tid;
            xa = x4[nb];         ma = m4[nb];
            xb = x4[nb + BLOCK]; mb = m4[nb + BLOCK];
        }
        acc += (cma.x ? cxa.x : 0.0f) + (cma.y ? cxa.y : 0.0f)
             + (cma.z ? cxa.z : 0.0f) + (cma.w ? cxa.w : 0.0f)
             + (cmb.x ? cxb.x : 0.0f) + (cmb.y ? cxb.y : 0.0f)
             + (cmb.z ? cxb.z : 0.0f) + (cmb.w ? cxb.w : 0.0f);
    }

    #pragma unroll
    for (int o = 32; o > 0; o >>= 1)
        acc += __shfl_xor(acc, o, 64);

    if (lane == 0) s_wsum[wave] = acc;
    __syncthreads();
    if (tid == 0)
        totals[bid] = s_wsum[0] + s_wsum[1] + s_wsum[2] + s_wsum[3];
}

// ---------------------------------------------------------------------------
// Kernel B: segment scan with running carry (8 pipelined chunks per block).
// ---------------------------------------------------------------------------
__global__ __launch_bounds__(BLOCK, 8)
void seg_scan(const float* __restrict__ x,
              const int*   __restrict__ mask,
              const float* __restrict__ totals,
              float*       __restrict__ out)
{
    __shared__ float s_ws[2][2][NWAVES];   // [chunk parity][sub-tile][wave]

    const int tid  = threadIdx.x;
    const int lane = tid & 63;
    const int wave = tid >> 6;
    const int bid  = blockIdx.x;
    const int row  = bid >> 3;
    const int seg  = bid & (SEGS - 1);

    const size_t base = (size_t)row * N_COLS + (size_t)seg * SEG;
    const float4* __restrict__ x4 = (const float4*)(x + base);
    const int4*   __restrict__ m4 = (const int4*)(mask + base);
    nativef4*     __restrict__ o4 = (nativef4*)(out + base);

    // Cross-segment prefix: sum of this row's totals[0..seg-1].
    // Uniform addresses (row/seg are block-uniform) -> scalar loads, L2-hot.
    float carry = 0.0f;
    const float* __restrict__ trow = totals + (row << 3);
    for (int i = 0; i < seg; ++i) carry += trow[i];

    // Prefetch chunk 0.
    float4 xa = x4[tid];
    int4   ma = m4[tid];
    float4 xb = x4[BLOCK + tid];
    int4   mb = m4[BLOCK + tid];

    for (int t = 0; t < ITERS; ++t) {
        const float4 cxa = xa; const int4 cma = ma;
        const float4 cxb = xb; const int4 cmb = mb;
        if (t + 1 < ITERS) {
            const int nb = (t + 1) * (2 * BLOCK) + tid;
            xa = x4[nb];         ma = m4[nb];
            xb = x4[nb + BLOCK]; mb = m4[nb + BLOCK];
        }

        // ---- sub-tile A: elems [0,1024) of chunk ----
        const float a0 = cma.x ? cxa.x : 0.0f;
        const float a1 = cma.y ? cxa.y : 0.0f;
        const float a2 = cma.z ? cxa.z : 0.0f;
        const float a3 = cma.w ? cxa.w : 0.0f;
        const float sa0 = a0;
        const float sa1 = sa0 + a1;
        const float sa2 = sa1 + a2;
        const float sa3 = sa2 + a3;
        const float inclA  = wave_incl_scan(sa3, lane);
        const float wexclA = inclA - sa3;

        // ---- sub-tile B: elems [1024,2048) of chunk ----
        const float b0 = cmb.x ? cxb.x : 0.0f;
        const float b1 = cmb.y ? cxb.y : 0.0f;
        const float b2 = cmb.z ? cxb.z : 0.0f;
        const float b3 = cmb.w ? cxb.w : 0.0f;
        const float sb0 = b0;
        const float sb1 = sb0 + b1;
        const float sb2 = sb1 + b2;
        const float sb3 = sb2 + b3;
        const float inclB  = wave_incl_scan(sb3, lane);
        const float wexclB = inclB - sb3;

        if (lane == 63) {
            s_ws[t & 1][0][wave] = inclA;
            s_ws[t & 1][1][wave] = inclB;
        }
        __syncthreads();

        float offA = 0.0f, totA = 0.0f, offB = 0.0f, totB = 0.0f;
        #pragma unroll
        for (int w = 0; w < NWAVES; ++w) {
            const float va = s_ws[t & 1][0][w];
            const float vb = s_ws[t & 1][1][w];
            if (w < wave) { offA += va; offB += vb; }
            totA += va;
            totB += vb;
        }

        const float baseA = carry + offA + wexclA;
        const float baseB = carry + totA + offB + wexclB;

        nativef4 ra, rb;
        ra.x = baseA + sa0;
        ra.y = baseA + sa1;
        ra.z = baseA + sa2;
        ra.w = baseA + sa3;
        rb.x = baseB + sb0;
        rb.y = baseB + sb1;
        rb.z = baseB + sb2;
        rb.w = baseB + sb3;
        const int ob = t * (2 * BLOCK) + tid;
        // NT: write-once stream; don't evict L3-resident x/mask.
        __builtin_nontemporal_store(ra, &o4[ob]);
        __builtin_nontemporal_store(rb, &o4[ob + BLOCK]);

        carry += totA + totB;
        // Parity double-buffer: next write to s_ws[t&1] is at t+2, after the
        // barrier at t+1 — no second barrier needed (round-0 verified trick).
    }
}

// ---------------------------------------------------------------------------
// Fallback: previous harness-verified kernel (314 us) — row-per-block, no
// workspace. Used only if d_ws is absent or too small for the totals buffer.
// ---------------------------------------------------------------------------
#define FB_BLOCK  1024
#define FB_VEC    4
#define FB_TILE   (FB_BLOCK * FB_VEC)   // 4096
#define FB_NTILES (N_COLS / FB_TILE)    // 32
#define FB_NWAVES (FB_BLOCK / 64)       // 16

__global__ __launch_bounds__(FB_BLOCK)
void masked_cumsum_fallback(const float* __restrict__ x,
                            const int* __restrict__ mask,
                            float* __restrict__ out) {
    __shared__ float waveSums[2][FB_NWAVES];

    const int row  = blockIdx.x;
    const int tid  = threadIdx.x;
    const int lane = tid & 63;
    const int wave = tid >> 6;

    const size_t rowBase = (size_t)row * N_COLS;
    const float4* __restrict__ x4 = (const float4*)(x + rowBase);
    const int4*   __restrict__ m4 = (const int4*)(mask + rowBase);
    float4*       __restrict__ o4 = (float4*)(out + rowBase);

    float carry = 0.0f;
    float4 xv = x4[tid];
    int4   mv = m4[tid];

    for (int t = 0; t < FB_NTILES; ++t) {
        const float4 cx = xv;
        const int4   cm = mv;
        if (t + 1 < FB_NTILES) {
            const int nidx = (t + 1) * FB_BLOCK + tid;
            xv = x4[nidx];
            mv = m4[nidx];
        }
        const float v0 = cm.x ? cx.x : 0.0f;
        const float v1 = cm.y ? cx.y : 0.0f;
        const float v2 = cm.z ? cx.z : 0.0f;
        const float v3 = cm.w ? cx.w : 0.0f;
        const float s0 = v0;
        const float s1 = s0 + v1;
        const float s2 = s1 + v2;
        const float s3 = s2 + v3;
        const float tsum = s3;

        float incl = tsum;
        #pragma unroll
        for (int d = 1; d < 64; d <<= 1) {
            const float y = __shfl_up(incl, d, 64);
            if (lane >= d) incl += y;
        }
        const float waveExcl = incl - tsum;

        if (lane == 63) waveSums[t & 1][wave] = incl;
        __syncthreads();

        float waveOff = 0.0f, tileTot = 0.0f;
        #pragma unroll
        for (int w = 0; w < FB_NWAVES; ++w) {
            const float s = waveSums[t & 1][w];
            if (w < wave) waveOff += s;
            tileTot += s;
        }

        const float base = carry + waveOff + waveExcl;
        float4 r;
        r.x = base + s0;
        r.y = base + s1;
        r.z = base + s2;
        r.w = base + s3;
        o4[t * FB_BLOCK + tid] = r;

        carry += tileTot;
    }
}

extern "C" void kernel_launch(void* const* d_in, const int* in_sizes, int n_in,
                              void* d_out, int out_size, void* d_ws, size_t ws_size,
                              hipStream_t stream) {
    const float* x    = (const float*)d_in[0];
    const int*   mask = (const int*)d_in[1];
    float*       out  = (float*)d_out;
    (void)in_sizes; (void)n_in; (void)out_size;

    const size_t need = (size_t)GRID_AB * sizeof(float);   // 8 KB
    if (d_ws != nullptr && ws_size >= need) {
        float* totals = (float*)d_ws;
        seg_totals<<<GRID_AB, BLOCK, 0, stream>>>(x, mask, totals);
        seg_scan<<<GRID_AB, BLOCK, 0, stream>>>(x, mask, totals, out);
    } else {
        masked_cumsum_fallback<<<B_ROWS, FB_BLOCK, 0, stream>>>(x, mask, out);
    }
}

// Round 9
// 323.036 us; speedup vs baseline: 1.1041x; 1.1041x over previous
//
#include <hip/hip_runtime.h>
#include <stdint.h>

// Masked cumulative sum along dim=1 — single-pass, wave-autonomous super-tiles.
//   x:    (256, 131072) float32
//   mask: (256, 131072) int32 (0/1)
//   out:  (256, 131072) float32
//
// Round-9: back to the minimal-traffic monolithic structure (read 268 MB once,
// write 134 MB once — A+B two-pass reads twice and its cold pass alone costs
// ~95-105 us, so its floor is worse than round-0's 120 us).
// Fixes round-0's measured loss (26% HBM util): its 32 per-tile
// __syncthreads each drained vmcnt(0) (compiler-enforced) with ~200cy of
// compute to hide it and 1 block/CU -> memory pipe idle at every barrier.
// New structure per 16384-elem super-tile:
//   * each of 16 waves owns a contiguous 1024-elem strip: 4 chunks x 256,
//     scanned serially with shuffle-only wave carries — NO block sync;
//   * scanned values held in registers (pre-offset);
//   * rolling prefetch: after consuming chunk c, issue next super-tile's
//     chunk-c loads (stays ~4 chunks in flight per thread);
//   * ONE barrier per super-tile (8/row instead of 32), and it's a NO-DRAIN
//     barrier: asm lgkmcnt(0) + raw s_barrier (only LDS consistency needed
//     for the 16 wave-sums) — prefetched global loads stay in flight across
//     it (the verified 8-phase-GEMM barrier pattern);
//   * block offset added post-barrier, output written with NT stores
//     (write-once stream; keep x/mask L3-resident — proven in kernel B).
// No workspace, no atomics, no inter-block deps: replay/graph-safe.

#define B_ROWS  256
#define N_COLS  131072
#define BLOCK   1024
#define NWAVES  16                  // waves per block
#define CHUNKS  4                   // chunks per wave per super-tile
#define STILE   (NWAVES * 64 * 4 * CHUNKS)   // 16384 elems per super-tile
#define NST     (N_COLS / STILE)    // 8 super-tiles per row

typedef float nativef4 __attribute__((ext_vector_type(4)));

__device__ __forceinline__ float wave_incl_scan(float v, int lane) {
    #pragma unroll
    for (int d = 1; d < 64; d <<= 1) {
        const float y = __shfl_up(v, d, 64);
        if (lane >= d) v += y;
    }
    return v;
}

__global__ __launch_bounds__(BLOCK, 4)
void masked_cumsum_fused(const float* __restrict__ x,
                         const int*   __restrict__ mask,
                         float*       __restrict__ out)
{
    __shared__ float wsum[2][NWAVES];   // parity double-buffered wave sums

    const int tid  = threadIdx.x;
    const int lane = tid & 63;
    const int wave = tid >> 6;
    const int row  = blockIdx.x;

    const size_t rowBase = (size_t)row * N_COLS;
    const float4* __restrict__ x4 = (const float4*)(x + rowBase);
    const int4*   __restrict__ m4 = (const int4*)(mask + rowBase);
    nativef4*     __restrict__ o4 = (nativef4*)(out + rowBase);

    // float4-index of chunk c of this thread within super-tile st:
    //   idx = st*4096 + wave*256 + c*64 + lane
    const int tb = wave * 256 + lane;

    // Prologue: load super-tile 0 (4 chunks), named regs (no arrays -> no
    // scratch risk, rule #20).
    float4 x0 = x4[tb];          int4 m0 = m4[tb];
    float4 x1 = x4[tb + 64];     int4 m1 = m4[tb + 64];
    float4 x2 = x4[tb + 128];    int4 m2 = m4[tb + 128];
    float4 x3 = x4[tb + 192];    int4 m3 = m4[tb + 192];

    float rowCarry = 0.0f;

    for (int st = 0; st < NST; ++st) {
        const int nb = (st + 1) * 4096 + tb;   // next super-tile base
        const bool more = (st + 1 < NST);
        float wcarry = 0.0f;
        nativef4 rv0, rv1, rv2, rv3;           // pre-offset scanned values

        // ---- chunk 0 ----
        {
            const float v0 = m0.x ? x0.x : 0.0f;
            const float v1 = m0.y ? x0.y : 0.0f;
            const float v2 = m0.z ? x0.z : 0.0f;
            const float v3 = m0.w ? x0.w : 0.0f;
            if (more) { x0 = x4[nb]; m0 = m4[nb]; }        // rolling prefetch
            const float s0 = v0, s1 = s0 + v1, s2 = s1 + v2, s3 = s2 + v3;
            const float incl = wave_incl_scan(s3, lane);
            const float base = wcarry + (incl - s3);
            rv0.x = base + s0; rv0.y = base + s1; rv0.z = base + s2; rv0.w = base + s3;
            wcarry += __shfl(incl, 63, 64);
        }
        // ---- chunk 1 ----
        {
            const float v0 = m1.x ? x1.x : 0.0f;
            const float v1 = m1.y ? x1.y : 0.0f;
            const float v2 = m1.z ? x1.z : 0.0f;
            const float v3 = m1.w ? x1.w : 0.0f;
            if (more) { x1 = x4[nb + 64]; m1 = m4[nb + 64]; }
            const float s0 = v0, s1 = s0 + v1, s2 = s1 + v2, s3 = s2 + v3;
            const float incl = wave_incl_scan(s3, lane);
            const float base = wcarry + (incl - s3);
            rv1.x = base + s0; rv1.y = base + s1; rv1.z = base + s2; rv1.w = base + s3;
            wcarry += __shfl(incl, 63, 64);
        }
        // ---- chunk 2 ----
        {
            const float v0 = m2.x ? x2.x : 0.0f;
            const float v1 = m2.y ? x2.y : 0.0f;
            const float v2 = m2.z ? x2.z : 0.0f;
            const float v3 = m2.w ? x2.w : 0.0f;
            if (more) { x2 = x4[nb + 128]; m2 = m4[nb + 128]; }
            const float s0 = v0, s1 = s0 + v1, s2 = s1 + v2, s3 = s2 + v3;
            const float incl = wave_incl_scan(s3, lane);
            const float base = wcarry + (incl - s3);
            rv2.x = base + s0; rv2.y = base + s1; rv2.z = base + s2; rv2.w = base + s3;
            wcarry += __shfl(incl, 63, 64);
        }
        // ---- chunk 3 ----
        {
            const float v0 = m3.x ? x3.x : 0.0f;
            const float v1 = m3.y ? x3.y : 0.0f;
            const float v2 = m3.z ? x3.z : 0.0f;
            const float v3 = m3.w ? x3.w : 0.0f;
            if (more) { x3 = x4[nb + 192]; m3 = m4[nb + 192]; }
            const float s0 = v0, s1 = s0 + v1, s2 = s1 + v2, s3 = s2 + v3;
            const float incl = wave_incl_scan(s3, lane);
            const float base = wcarry + (incl - s3);
            rv3.x = base + s0; rv3.y = base + s1; rv3.z = base + s2; rv3.w = base + s3;
            wcarry += __shfl(incl, 63, 64);
        }

        // ---- block combine: ONE no-drain barrier per super-tile ----
        if (lane == 0) wsum[st & 1][wave] = wcarry;
        // Only LDS consistency is needed; do NOT drain vmcnt (prefetched
        // global loads stay in flight across the barrier).
        asm volatile("s_waitcnt lgkmcnt(0)" ::: "memory");
        __builtin_amdgcn_s_barrier();
        asm volatile("" ::: "memory");

        float woff = 0.0f, btot = 0.0f;
        #pragma unroll
        for (int w = 0; w < NWAVES; ++w) {
            const float s = wsum[st & 1][w];
            if (w < wave) woff += s;
            btot += s;
        }
        const float addv = rowCarry + woff;

        const int ob = st * 4096 + tb;
        rv0.x += addv; rv0.y += addv; rv0.z += addv; rv0.w += addv;
        rv1.x += addv; rv1.y += addv; rv1.z += addv; rv1.w += addv;
        rv2.x += addv; rv2.y += addv; rv2.z += addv; rv2.w += addv;
        rv3.x += addv; rv3.y += addv; rv3.z += addv; rv3.w += addv;
        __builtin_nontemporal_store(rv0, &o4[ob]);
        __builtin_nontemporal_store(rv1, &o4[ob + 64]);
        __builtin_nontemporal_store(rv2, &o4[ob + 128]);
        __builtin_nontemporal_store(rv3, &o4[ob + 192]);

        rowCarry += btot;
        // Parity double-buffer on wsum: the write to wsum[(st+1)&1] happens
        // after this barrier; the next write to wsum[st&1] is gated by the
        // NEXT barrier, which readers of wsum[st&1] have already passed.
    }
}

extern "C" void kernel_launch(void* const* d_in, const int* in_sizes, int n_in,
                              void* d_out, int out_size, void* d_ws, size_t ws_size,
                              hipStream_t stream) {
    const float* x    = (const float*)d_in[0];
    const int*   mask = (const int*)d_in[1];
    float*       out  = (float*)d_out;
    (void)in_sizes; (void)n_in; (void)out_size; (void)d_ws; (void)ws_size;

    masked_cumsum_fused<<<B_ROWS, BLOCK, 0, stream>>>(x, mask, out);
}

// Round 10
// 313.928 us; speedup vs baseline: 1.1361x; 1.0290x over previous
//
#include <hip/hip_runtime.h>
#include <stdint.h>

// Masked cumulative sum along dim=1 — round-0 structure + DEPTH-4 prefetch.
//   x:    (256, 131072) float32
//   mask: (256, 131072) int32 (0/1)
//   out:  (256, 131072) float32
//
// Round-10: single-mechanism experiment. Nine structures all pin cold-read
// effective BW at 2-3.3 TB/s vs the 6.3 TB/s copy ceiling; best model is
// in-flight-bytes limited (BW = bytes_in_flight / effective_latency).
// Round-0 held only 2 loads/thread outstanding (32 KB/CU). This kernel is
// round-0 verbatim (4096-elem tiles, per-tile wave scan + LDS wave-sum
// combine, parity double-buffered, plain float4 stores) with:
//   * FOUR named load-slot pairs (xa/ma..xd/md), rotated by a 4-unrolled
//     group loop -> 8 loads outstanding per thread = 128 KB/CU in flight.
//     Named slots, not arrays (rule #20: runtime-indexed arrays -> scratch).
//   * NO-DRAIN barrier: asm lgkmcnt(0) + raw s_barrier instead of
//     __syncthreads. __syncthreads emits s_waitcnt vmcnt(0) which would
//     drain the deep pipeline at EVERY tile (32x/row), nullifying the
//     mechanism. Only LDS consistency (16 wave-sums) is needed at the
//     barrier; global loads/stores are thread-private/disjoint. This
//     barrier pattern ran correctly in round 9 (passed, absmax identical).
// No workspace, no atomics, no inter-block deps; replay/graph-safe.
//
// Decision rule: ~120 us unchanged with VGPR>=64 -> per-CU request-rate
// ceiling (structure-independent) -> declare roofline next round.

#define N_ROWS   256
#define N_COLS   131072
#define BLOCK    1024
#define VEC      4
#define TILE     (BLOCK * VEC)      // 4096 elems
#define NTILES   (N_COLS / TILE)    // 32
#define NWAVES   (BLOCK / 64)       // 16
#define DEPTH    4                  // tiles in flight

__global__ __launch_bounds__(BLOCK, 4)
void masked_cumsum_deep(const float* __restrict__ x,
                        const int*   __restrict__ mask,
                        float*       __restrict__ out)
{
    __shared__ float wsum[2][NWAVES];

    const int tid  = threadIdx.x;
    const int lane = tid & 63;
    const int wave = tid >> 6;
    const int row  = blockIdx.x;

    const size_t rowBase = (size_t)row * N_COLS;
    const float4* __restrict__ x4 = (const float4*)(x + rowBase);
    const int4*   __restrict__ m4 = (const int4*)(mask + rowBase);
    float4*       __restrict__ o4 = (float4*)(out + rowBase);

    float carry = 0.0f;

    // Prologue: tiles 0..3 in flight (8 load instructions).
    float4 xa = x4[tid];              int4 ma = m4[tid];
    float4 xb = x4[BLOCK + tid];      int4 mb = m4[BLOCK + tid];
    float4 xc = x4[2 * BLOCK + tid];  int4 mc = m4[2 * BLOCK + tid];
    float4 xd = x4[3 * BLOCK + tid];  int4 md = m4[3 * BLOCK + tid];

    // One tile: consume slot, refill slot with tile T+DEPTH, scan, combine,
    // store. Barrier is LDS-only (no vmcnt drain) so the other 6-9 VMEM ops
    // stay in flight across it.
    #define STEP(XS, MS, T)                                                  \
    do {                                                                     \
        const float4 cx = XS;                                                \
        const int4   cm = MS;                                                \
        if ((T) + DEPTH < NTILES) {                                          \
            const int ni = ((T) + DEPTH) * BLOCK + tid;                      \
            XS = x4[ni];                                                     \
            MS = m4[ni];                                                     \
        }                                                                    \
        const float v0 = cm.x ? cx.x : 0.0f;                                 \
        const float v1 = cm.y ? cx.y : 0.0f;                                 \
        const float v2 = cm.z ? cx.z : 0.0f;                                 \
        const float v3 = cm.w ? cx.w : 0.0f;                                 \
        const float s0 = v0;                                                 \
        const float s1 = s0 + v1;                                            \
        const float s2 = s1 + v2;                                            \
        const float s3 = s2 + v3;                                            \
        float incl = s3;                                                     \
        _Pragma("unroll")                                                    \
        for (int d = 1; d < 64; d <<= 1) {                                   \
            const float y = __shfl_up(incl, d, 64);                          \
            if (lane >= d) incl += y;                                        \
        }                                                                    \
        const float wexcl = incl - s3;                                       \
        if (lane == 63) wsum[(T) & 1][wave] = incl;                          \
        asm volatile("s_waitcnt lgkmcnt(0)" ::: "memory");                   \
        __builtin_amdgcn_s_barrier();                                        \
        asm volatile("" ::: "memory");                                       \
        float woff = 0.0f, ttot = 0.0f;                                      \
        _Pragma("unroll")                                                    \
        for (int w = 0; w < NWAVES; ++w) {                                   \
            const float s = wsum[(T) & 1][w];                                \
            if (w < wave) woff += s;                                         \
            ttot += s;                                                       \
        }                                                                    \
        const float basev = carry + woff + wexcl;                            \
        float4 r;                                                            \
        r.x = basev + s0;                                                    \
        r.y = basev + s1;                                                    \
        r.z = basev + s2;                                                    \
        r.w = basev + s3;                                                    \
        o4[(T) * BLOCK + tid] = r;                                           \
        carry += ttot;                                                       \
    } while (0)
    // Parity double-buffer on wsum: reader of wsum[T&1] finishes before its
    // barrier(T+1) crossing; the next writer of wsum[T&1] (at T+2) writes
    // after crossing barrier(T+1) -> s_barrier orders them (round-0/round-9
    // verified pattern).

    for (int g = 0; g < NTILES / DEPTH; ++g) {
        const int t0 = g * DEPTH;
        STEP(xa, ma, t0 + 0);
        STEP(xb, mb, t0 + 1);
        STEP(xc, mc, t0 + 2);
        STEP(xd, md, t0 + 3);
    }
    #undef STEP
}

extern "C" void kernel_launch(void* const* d_in, const int* in_sizes, int n_in,
                              void* d_out, int out_size, void* d_ws, size_t ws_size,
                              hipStream_t stream) {
    const float* x    = (const float*)d_in[0];
    const int*   mask = (const int*)d_in[1];
    float*       out  = (float*)d_out;
    (void)in_sizes; (void)n_in; (void)out_size; (void)d_ws; (void)ws_size;

    masked_cumsum_deep<<<N_ROWS, BLOCK, 0, stream>>>(x, mask, out);
}